// Round 9
// baseline (187.030 us; speedup 1.0000x reference)
//
#include <hip/hip_runtime.h>
#include <stdint.h>

#define Bdim 4
#define Ldim 512
#define Hdim 768
#define Edim 10
#define Rdim 10

typedef __attribute__((ext_vector_type(8))) short short8;
typedef __attribute__((ext_vector_type(4))) float floatx4;

__device__ __forceinline__ unsigned short f2bf(float x) {
    unsigned int u = __float_as_uint(x);
    unsigned int r = (u + 0x7fffu + ((u >> 16) & 1u)) >> 16;
    return (unsigned short)r;
}
__device__ __forceinline__ float bf2f(unsigned short u) {
    return __uint_as_float(((unsigned int)u) << 16);
}

#define GLOAD_LDS16(g, l)                                                      \
    __builtin_amdgcn_global_load_lds(                                          \
        (const __attribute__((address_space(1))) void*)(g),                    \
        (__attribute__((address_space(3))) void*)(l), 16, 0, 0)

#define WAITVM(n) asm volatile("s_waitcnt vmcnt(" #n ")" ::: "memory")

// bijective XCD remap of a linear block id (nwg must be %8==0)
__device__ __forceinline__ int xcd_swz(int bid, int nwg) {
    int cpx = nwg >> 3;
    return (bid & 7) * cpx + (bid >> 3);
}

// ====== 256^2 core, BK=64, dbuf, counted vmcnt (R7 — unchanged) =============
__device__ __forceinline__ void gemm_bt_core256_cnt(
    const unsigned short* __restrict__ A, int lda,
    const unsigned short* __restrict__ Bm, int ldb,
    unsigned short* lA, unsigned short* lB,
    floatx4 acc[8][4])
{
    const int tid  = threadIdx.x;       // 0..511
    const int lane = tid & 63;
    const int wave = tid >> 6;          // 0..7
    const int wr = wave >> 2;           // 0..1  (M)
    const int wc = wave & 3;            // 0..3  (N)

    const int srow   = tid >> 3;                  // 0..63
    const int schunk = (tid & 7) ^ (srow & 7);    // pre-swizzled k-chunk
    const int skk    = schunk << 3;

    const int frow = lane & 15;
    const int fs   = lane >> 4;                   // 0..3

    #define STAGE256(t, buf)                                                   \
        do {                                                                   \
            const int k0s = (t) << 6;                                          \
            unsigned short* dA = lA + (buf) * 16384;                           \
            unsigned short* dB = lB + (buf) * 16384;                           \
            _Pragma("unroll")                                                  \
            for (int i = 0; i < 4; ++i) {                                      \
                GLOAD_LDS16(A  + (size_t)(srow + 64 * i) * lda + k0s + skk,    \
                            dA + (tid + 512 * i) * 8);                         \
                GLOAD_LDS16(Bm + (size_t)(srow + 64 * i) * ldb + k0s + skk,    \
                            dB + (tid + 512 * i) * 8);                         \
            }                                                                  \
        } while (0)

    #define COMPUTE256(buf)                                                    \
        do {                                                                   \
            const unsigned short* sA = lA + (buf) * 16384;                     \
            const unsigned short* sB = lB + (buf) * 16384;                     \
            _Pragma("unroll")                                                  \
            for (int h = 0; h < 2; ++h) {                                      \
                short8 bfr[4];                                                 \
                _Pragma("unroll")                                              \
                for (int ni = 0; ni < 4; ++ni) {                               \
                    int row  = wc * 64 + ni * 16 + frow;                       \
                    int slot = (fs + 4 * h) ^ (row & 7);                       \
                    bfr[ni] = *reinterpret_cast<const short8*>(                \
                        sB + row * 64 + slot * 8);                             \
                }                                                              \
                _Pragma("unroll")                                              \
                for (int mi = 0; mi < 8; ++mi) {                               \
                    int row  = wr * 128 + mi * 16 + frow;                      \
                    int slot = (fs + 4 * h) ^ (row & 7);                       \
                    short8 af = *reinterpret_cast<const short8*>(              \
                        sA + row * 64 + slot * 8);                             \
                    _Pragma("unroll")                                          \
                    for (int ni = 0; ni < 4; ++ni)                             \
                        acc[mi][ni] = __builtin_amdgcn_mfma_f32_16x16x32_bf16( \
                            af, bfr[ni], acc[mi][ni], 0, 0, 0);                \
                }                                                              \
            }                                                                  \
        } while (0)

    const int NT = Hdim >> 6;   // 12

    STAGE256(0, 0);
    for (int kt = 0; kt < NT - 1; ++kt) {
        __builtin_amdgcn_s_barrier();          // readers of tile kt-1 done
        STAGE256(kt + 1, (kt + 1) & 1);        // overwrite tile kt-1's buffer
        WAITVM(8);                             // tile kt landed; kt+1 in flight
        __builtin_amdgcn_s_barrier();          // all waves have tile kt
        __builtin_amdgcn_sched_barrier(0);
        COMPUTE256(kt & 1);
    }
    __builtin_amdgcn_s_barrier();
    WAITVM(0);
    __builtin_amdgcn_s_barrier();
    __builtin_amdgcn_sched_barrier(0);
    COMPUTE256((NT - 1) & 1);

    #undef STAGE256
    #undef COMPUTE256
}

// ================= k_prep: proj (f32-direct) + cvt(Wbil,We), fused ==========
__global__ __launch_bounds__(256) void k_prep(
    const float* __restrict__ h,   const float* __restrict__ Wp,
    const float* __restrict__ bproj,
    const float* __restrict__ Wbil, const float* __restrict__ We,
    unsigned short* __restrict__ hp,
    unsigned short* __restrict__ Wb_bf, unsigned short* __restrict__ We_bf)
{
    __shared__ unsigned short lA[128 * 64];
    __shared__ unsigned short lB[128 * 64];
    const int tid = threadIdx.x;

    if (blockIdx.x >= 96) {
        const int n2 = Rdim * Hdim * Hdim / 4;
        const int n3 = Edim * Hdim / 4;
        int i = (blockIdx.x - 96) * 256 + tid;
        const int stride = (gridDim.x - 96) * 256;
        for (; i < n2 + n3; i += stride) {
            const float* s; unsigned short* d; int j = i;
            if (j < n2) { s = Wbil; d = Wb_bf; }
            else { j -= n2; s = We; d = We_bf; }
            float4 v = reinterpret_cast<const float4*>(s)[j];
            ushort4 o;
            o.x = f2bf(v.x); o.y = f2bf(v.y); o.z = f2bf(v.z); o.w = f2bf(v.w);
            reinterpret_cast<ushort4*>(d)[j] = o;
        }
        return;
    }

    int bid = xcd_swz(blockIdx.x, 96);
    const int m0 = (bid % 16) * 128;
    const int n0 = (bid / 16) * 128;
    const float* Asrc = h  + (size_t)m0 * Hdim;
    const float* Bsrc = Wp + (size_t)n0 * Hdim;

    const int lane = tid & 63;
    const int wave = tid >> 6;
    const int wr = wave >> 1, wc = wave & 1;
    const int frow = lane & 15;
    const int fs   = lane >> 4;

    floatx4 acc[4][4];
    #pragma unroll
    for (int i = 0; i < 4; ++i)
        #pragma unroll
        for (int j = 0; j < 4; ++j)
            acc[i][j] = (floatx4){0.f, 0.f, 0.f, 0.f};

    float4 ra[4][2], rb[4][2];
    #define LOADREGS(k0s)                                                      \
        _Pragma("unroll")                                                      \
        for (int i = 0; i < 4; ++i) {                                          \
            int q = tid + 256 * i, row = q >> 3, pchk = q & 7;                 \
            int lchk = pchk ^ (row & 7);                                       \
            const float* sa = Asrc + (size_t)row * Hdim + (k0s) + lchk * 8;    \
            const float* sb = Bsrc + (size_t)row * Hdim + (k0s) + lchk * 8;    \
            ra[i][0] = *reinterpret_cast<const float4*>(sa);                   \
            ra[i][1] = *reinterpret_cast<const float4*>(sa + 4);               \
            rb[i][0] = *reinterpret_cast<const float4*>(sb);                   \
            rb[i][1] = *reinterpret_cast<const float4*>(sb + 4);               \
        }

    LOADREGS(0);
    const int NT = Hdim >> 6;    // 12
    for (int kt = 0; kt < NT; ++kt) {
        short8 pa[4], pb[4];
        #pragma unroll
        for (int i = 0; i < 4; ++i) {
            pa[i][0] = f2bf(ra[i][0].x); pa[i][1] = f2bf(ra[i][0].y);
            pa[i][2] = f2bf(ra[i][0].z); pa[i][3] = f2bf(ra[i][0].w);
            pa[i][4] = f2bf(ra[i][1].x); pa[i][5] = f2bf(ra[i][1].y);
            pa[i][6] = f2bf(ra[i][1].z); pa[i][7] = f2bf(ra[i][1].w);
            pb[i][0] = f2bf(rb[i][0].x); pb[i][1] = f2bf(rb[i][0].y);
            pb[i][2] = f2bf(rb[i][0].z); pb[i][3] = f2bf(rb[i][0].w);
            pb[i][4] = f2bf(rb[i][1].x); pb[i][5] = f2bf(rb[i][1].y);
            pb[i][6] = f2bf(rb[i][1].z); pb[i][7] = f2bf(rb[i][1].w);
        }
        __syncthreads();
        #pragma unroll
        for (int i = 0; i < 4; ++i) {
            int q = tid + 256 * i, row = q >> 3, pchk = q & 7;
            *reinterpret_cast<short8*>(lA + row * 64 + pchk * 8) = pa[i];
            *reinterpret_cast<short8*>(lB + row * 64 + pchk * 8) = pb[i];
        }
        if (kt + 1 < NT) LOADREGS((kt + 1) << 6);
        __syncthreads();
        #pragma unroll
        for (int hh = 0; hh < 2; ++hh) {
            short8 af[4], bfr[4];
            #pragma unroll
            for (int mi = 0; mi < 4; ++mi) {
                int row  = wr * 64 + mi * 16 + frow;
                int slot = (fs + 4 * hh) ^ (row & 7);
                af[mi] = *reinterpret_cast<const short8*>(lA + row * 64 + slot * 8);
            }
            #pragma unroll
            for (int ni = 0; ni < 4; ++ni) {
                int row  = wc * 64 + ni * 16 + frow;
                int slot = (fs + 4 * hh) ^ (row & 7);
                bfr[ni] = *reinterpret_cast<const short8*>(lB + row * 64 + slot * 8);
            }
            #pragma unroll
            for (int mi = 0; mi < 4; ++mi)
                #pragma unroll
                for (int ni = 0; ni < 4; ++ni)
                    acc[mi][ni] = __builtin_amdgcn_mfma_f32_16x16x32_bf16(
                        af[mi], bfr[ni], acc[mi][ni], 0, 0, 0);
        }
    }
    #undef LOADREGS

    const int cl = lane & 15, rh = (lane >> 4) * 4;
    #pragma unroll
    for (int mi = 0; mi < 4; ++mi)
        #pragma unroll
        for (int ni = 0; ni < 4; ++ni)
            #pragma unroll
            for (int j = 0; j < 4; ++j) {
                int r = m0 + wr * 64 + mi * 16 + rh + j;
                int c = n0 + wc * 64 + ni * 16 + cl;
                float v = acc[mi][ni][j] + bproj[c];
                hp[(size_t)r * Hdim + c] = f2bf(fmaxf(v, 0.0f));
            }
}

// ---- k_gemm_t_ent: gemm_t (blocks 0..239) + ent_logits (blocks 240..271) ---
__global__ __launch_bounds__(512, 1) void k_gemm_t_ent(
    const unsigned short* __restrict__ hp,
    const unsigned short* __restrict__ Wb,
    unsigned short* __restrict__ T,
    const unsigned short* __restrict__ We,
    const float* __restrict__ bent,
    float* __restrict__ out_ent)
{
    __shared__ unsigned short lA[2 * 256 * 64];
    __shared__ unsigned short lB[2 * 256 * 64];
    const int tid = threadIdx.x, lane = tid & 63, wave = tid >> 6;

    if (blockIdx.x >= 240) {
        // ---- ent: 32 blocks x 8 waves x 8 rows = 2048 rows ----
        const int base = ((blockIdx.x - 240) * 8 + wave) * 8;
        for (int rr = 0; rr < 8; ++rr) {
            const unsigned short* row = hp + (size_t)(base + rr) * Hdim;
            float hv[12];
            #pragma unroll
            for (int j = 0; j < 12; ++j) hv[j] = bf2f(row[lane + j * 64]);
            #pragma unroll
            for (int ee = 0; ee < Edim; ++ee) {
                const unsigned short* wrow = We + ee * Hdim;
                float s = 0.f;
                #pragma unroll
                for (int j = 0; j < 12; ++j) s += hv[j] * bf2f(wrow[lane + j * 64]);
                #pragma unroll
                for (int off = 32; off >= 1; off >>= 1) s += __shfl_xor(s, off);
                if (lane == 0) out_ent[(size_t)(base + rr) * Edim + ee] = s + bent[ee];
            }
        }
        return;
    }

    int bid = xcd_swz(blockIdx.x, 240);
    const int m0 = (bid % 8) * 256;
    const int n0 = (bid / 8) * 256;   // over R*H = 7680
    floatx4 acc[8][4];
    #pragma unroll
    for (int i = 0; i < 8; ++i)
        #pragma unroll
        for (int j = 0; j < 4; ++j)
            acc[i][j] = (floatx4){0.f, 0.f, 0.f, 0.f};

    gemm_bt_core256_cnt(hp + (size_t)m0 * Hdim, Hdim,
                        Wb + (size_t)n0 * Hdim, Hdim, lA, lB, acc);

    const int wr = wave >> 2, wc = wave & 3;
    const int cl = lane & 15, rh = (lane >> 4) * 4;
    #pragma unroll
    for (int mi = 0; mi < 8; ++mi)
        #pragma unroll
        for (int ni = 0; ni < 4; ++ni)
            #pragma unroll
            for (int j = 0; j < 4; ++j) {
                int r = m0 + wr * 128 + mi * 16 + rh + j;
                int c = n0 + wc * 64 + ni * 16 + cl;
                T[(size_t)r * (Rdim * Hdim) + c] = f2bf(acc[mi][ni][j]);
            }
}

// ---- k_rel: 256x160 tiles -> exactly 256 blocks (1 per CU) -----------------
// rel[grow, n] = sum_k hp[grow,k] * T2[b, n, k] + bbil[n%10],
// grow = b*512+l (M=2048, tiles of 256), n = m*10+r (N=5120, tiles of 160).
// Waves: 4M x 2N; per-wave 64x80 output, acc[4][5].
// LDS: A dbuf 2x[256][64] (64KB), B dbuf 2x[192][64] (48KB) - rows 160..191
// staged from remapped in-bounds sources, never read.
__global__ __launch_bounds__(512, 1) void k_rel(
    const unsigned short* __restrict__ hp,
    const unsigned short* __restrict__ T,
    const float* __restrict__ bbil,
    float* __restrict__ rel)
{
    __shared__ unsigned short lA[2 * 256 * 64];   // 64KB
    __shared__ unsigned short lB[2 * 192 * 64];   // 48KB
    const int tid = threadIdx.x, lane = tid & 63, wave = tid >> 6;
    const int wr = wave >> 1;          // 0..3 (M)
    const int wv = wave & 1;           // 0..1 (N)

    int bid = xcd_swz(blockIdx.x, 256);
    const int m0 = (bid & 7) * 256;           // 8 M-tiles
    const int n0 = (bid >> 3) * 160;          // 32 N-tiles
    const int b  = m0 >> 9;

    const unsigned short* A  = hp + (size_t)m0 * Hdim;
    const unsigned short* Bm = T + (size_t)b * Ldim * (Rdim * Hdim) + (size_t)n0 * Hdim;

    const int srow   = tid >> 3;                  // 0..63
    const int schunk = (tid & 7) ^ (srow & 7);
    const int skk    = schunk << 3;
    // B row for instr i=2 (LDS rows 128..191): remap rows >=160 in-bounds
    const int brow2  = (srow >= 32) ? (srow + 64) : (srow + 128);

    const int frow = lane & 15;
    const int fs   = lane >> 4;

    floatx4 acc[4][5];
    #pragma unroll
    for (int i = 0; i < 4; ++i)
        #pragma unroll
        for (int j = 0; j < 5; ++j)
            acc[i][j] = (floatx4){0.f, 0.f, 0.f, 0.f};

    #define STAGE_R(t, buf)                                                    \
        do {                                                                   \
            const int k0s = (t) << 6;                                          \
            unsigned short* dA = lA + (buf) * 16384;                           \
            unsigned short* dB = lB + (buf) * 12288;                           \
            _Pragma("unroll")                                                  \
            for (int i = 0; i < 4; ++i)                                        \
                GLOAD_LDS16(A + (size_t)(srow + 64 * i) * Hdim + k0s + skk,    \
                            dA + (tid + 512 * i) * 8);                         \
            GLOAD_LDS16(Bm + (size_t)srow * Hdim + k0s + skk,                  \
                        dB + tid * 8);                                         \
            GLOAD_LDS16(Bm + (size_t)(srow + 64) * Hdim + k0s + skk,           \
                        dB + (tid + 512) * 8);                                 \
            GLOAD_LDS16(Bm + (size_t)brow2 * Hdim + k0s + skk,                 \
                        dB + (tid + 1024) * 8);                                \
        } while (0)

    #define COMPUTE_R(buf)                                                     \
        do {                                                                   \
            const unsigned short* sA = lA + (buf) * 16384;                     \
            const unsigned short* sB = lB + (buf) * 12288;                     \
            _Pragma("unroll")                                                  \
            for (int h = 0; h < 2; ++h) {                                      \
                short8 bfr[5];                                                 \
                _Pragma("unroll")                                              \
                for (int ni = 0; ni < 5; ++ni) {                               \
                    int row  = wv * 80 + ni * 16 + frow;                       \
                    int slot = (fs + 4 * h) ^ (row & 7);                       \
                    bfr[ni] = *reinterpret_cast<const short8*>(                \
                        sB + row * 64 + slot * 8);                             \
                }                                                              \
                _Pragma("unroll")                                              \
                for (int mi = 0; mi < 4; ++mi) {                               \
                    int row  = wr * 64 + mi * 16 + frow;                       \
                    int slot = (fs + 4 * h) ^ (row & 7);                       \
                    short8 af = *reinterpret_cast<const short8*>(              \
                        sA + row * 64 + slot * 8);                             \
                    _Pragma("unroll")                                          \
                    for (int ni = 0; ni < 5; ++ni)                             \
                        acc[mi][ni] = __builtin_amdgcn_mfma_f32_16x16x32_bf16( \
                            af, bfr[ni], acc[mi][ni], 0, 0, 0);                \
                }                                                              \
            }                                                                  \
        } while (0)

    const int NT = Hdim >> 6;   // 12
    STAGE_R(0, 0);
    for (int kt = 0; kt < NT - 1; ++kt) {
        __builtin_amdgcn_s_barrier();
        STAGE_R(kt + 1, (kt + 1) & 1);
        WAITVM(7);                             // this K-tile's 7 loads landed
        __builtin_amdgcn_s_barrier();
        __builtin_amdgcn_sched_barrier(0);
        COMPUTE_R(kt & 1);
    }
    __builtin_amdgcn_s_barrier();
    WAITVM(0);
    __builtin_amdgcn_s_barrier();
    __builtin_amdgcn_sched_barrier(0);
    COMPUTE_R((NT - 1) & 1);
    #undef STAGE_R
    #undef COMPUTE_R

    const int cl = lane & 15, rh = (lane >> 4) * 4;
    #pragma unroll
    for (int mi = 0; mi < 4; ++mi)
        #pragma unroll
        for (int ni = 0; ni < 5; ++ni) {
            int n = n0 + wv * 80 + ni * 16 + cl;
            float bias = bbil[n % Rdim];
            #pragma unroll
            for (int j = 0; j < 4; ++j) {
                int grow = m0 + wr * 64 + mi * 16 + rh + j;
                rel[(size_t)grow * (Ldim * Rdim) + n] = acc[mi][ni][j] + bias;
            }
        }
}

extern "C" void kernel_launch(void* const* d_in, const int* in_sizes, int n_in,
                              void* d_out, int out_size, void* d_ws, size_t ws_size,
                              hipStream_t stream)
{
    const float* h     = (const float*)d_in[0];
    const float* Wproj = (const float*)d_in[1];
    const float* bproj = (const float*)d_in[2];
    const float* Went  = (const float*)d_in[3];
    const float* bent  = (const float*)d_in[4];
    const float* Wbil  = (const float*)d_in[5];
    const float* bbil  = (const float*)d_in[6];

    float* out_ent = (float*)d_out;
    float* out_rel = (float*)d_out + (size_t)Bdim * Ldim * Edim;

    unsigned short* Wb_bf = (unsigned short*)d_ws;
    unsigned short* We_bf = Wb_bf + (size_t)Rdim * Hdim * Hdim;
    unsigned short* hp_bf = We_bf + (size_t)Edim * Hdim;
    unsigned short* T_bf  = hp_bf + (size_t)2048 * Hdim;   // 2048 x 7680

    // 1) fused: proj (f32-direct, blocks 0..95) + cvt Wbil/We (96..1119)
    k_prep<<<dim3(1120), 256, 0, stream>>>(h, Wproj, bproj, Wbil, Went,
                                           hp_bf, Wb_bf, We_bf);

    // 2) gemm_t (240 blocks) + ent (32 blocks) in one launch
    k_gemm_t_ent<<<dim3(272), 512, 0, stream>>>(hp_bf, Wb_bf, T_bf,
                                                We_bf, bent, out_ent);

    // 3) rel: 256x160 tiles, exactly 256 blocks (full CU coverage)
    k_rel<<<dim3(256), 512, 0, stream>>>(hp_bf, T_bf, bbil, out_rel);
}